// Round 4
// baseline (550.748 us; speedup 1.0000x reference)
//
#include <hip/hip_runtime.h>
#include <cstdint>
#include <cstddef>

#define B_ 16
#define L_ 200
#define H_ 64
#define NH_ 2
#define D_ 32   // head dim

// ---------------------------------------------------------------------------
// Kernel A: fused QKV projection.
//   QM = queries @ Wq^T + bq
//   KM = keys    @ Wk^T + bk + abs_pos_K      (K + pK folded, split is a reshape)
//   VM = keys    @ Wv^T + bv + abs_pos_V      (V + pV folded)
// One block = 4 (b,l) rows; W matrices staged in LDS padded to 65 floats/row
// so the per-thread row read sW[t][j] is bank-conflict-free (65 mod 32 == 1).
// ---------------------------------------------------------------------------
__global__ __launch_bounds__(256) void proj_kernel(
    const float* __restrict__ queries, const float* __restrict__ keys,
    const float* __restrict__ absK, const float* __restrict__ absV,
    const float* __restrict__ Wq, const float* __restrict__ bq,
    const float* __restrict__ Wk, const float* __restrict__ bk,
    const float* __restrict__ Wv, const float* __restrict__ bv,
    float* __restrict__ QM, float* __restrict__ KM, float* __restrict__ VM)
{
    __shared__ float sW[3][64][65];
    __shared__ float sRow[2][4][64];

    const int tid = threadIdx.x;
    const int bl0 = blockIdx.x * 4;

    for (int i = tid; i < 64 * 64; i += 256) {
        const int r = i >> 6, c = i & 63;
        sW[0][r][c] = Wq[i];
        sW[1][r][c] = Wk[i];
        sW[2][r][c] = Wv[i];
    }
    const int rr = tid >> 6;     // which of the 4 rows
    const int t  = tid & 63;     // output channel
    sRow[0][rr][t] = queries[(size_t)(bl0 + rr) * 64 + t];
    sRow[1][rr][t] = keys   [(size_t)(bl0 + rr) * 64 + t];
    __syncthreads();

    float accq = bq[t], acck = bk[t], accv = bv[t];
#pragma unroll
    for (int j = 0; j < 64; j++) {
        const float qv = sRow[0][rr][j];
        const float kv = sRow[1][rr][j];
        accq += qv * sW[0][t][j];
        acck += kv * sW[1][t][j];
        accv += kv * sW[2][t][j];
    }
    const size_t idx = (size_t)(bl0 + rr) * 64 + t;
    QM[idx] = accq;
    KM[idx] = acck + absK[idx];
    VM[idx] = accv + absV[idx];
}

// ---------------------------------------------------------------------------
// Kernel B: fused attention. One block per (b,q); 256 threads.
// Thread layout: c4 = tid&15 (owns channels c=4*c4..4*c4+3, float4 loads),
//                krow = tid>>4 (16 k's in flight per chunk).
// score[h,k] = (1/sqrt(32)) * sum_c Q[c]*(KM[k,c]+tK[b,q,k,c]+dK[b,q,k,c])
// out[c]     = sum_k A[h,k]*(VM[k,c]+tV[b,q,k,c]+dV[b,q,k,c])
// Big tensors (655 MB total) are read exactly once, coalesced float4.
// MASKS ARE INT32: harness uploads integer (incl. bool) inputs as int32.
// ---------------------------------------------------------------------------
__global__ __launch_bounds__(256) void attn_kernel(
    const float* __restrict__ QM, const float* __restrict__ KM, const float* __restrict__ VM,
    const float* __restrict__ tK, const float* __restrict__ dK,
    const float* __restrict__ tV, const float* __restrict__ dV,
    const int* __restrict__ time_mask, const int* __restrict__ attn_mask,
    float* __restrict__ out)
{
    const int tid  = threadIdx.x;
    const int bq   = blockIdx.x;          // b*L + q
    const int b    = bq / L_;
    const int q    = bq - b * L_;
    const int c4   = tid & 15;
    const int krow = tid >> 4;            // 0..15
    const int c    = c4 * 4;
    const int h    = c4 >> 3;             // head of this thread's channels

    __shared__ float sScore[NH_][208];    // scores -> probs (padded)
    __shared__ float sRed[16][64];        // PV cross-krow reduction
    __shared__ float sQ[64];

    if (tid < 64) sQ[tid] = QM[(size_t)bq * 64 + tid];
    __syncthreads();
    const float qv0 = sQ[c], qv1 = sQ[c + 1], qv2 = sQ[c + 2], qv3 = sQ[c + 3];

    const size_t bigbase = (size_t)bq * L_ * 64;   // ((b*L+q)*L + k)*64

    // ---- scores ----
    for (int k0 = 0; k0 < L_; k0 += 16) {
        const int k = k0 + krow;
        if (k < L_) {
            const size_t off = bigbase + (size_t)k * 64 + c;
            const float4 t1 = *reinterpret_cast<const float4*>(tK + off);
            const float4 t2 = *reinterpret_cast<const float4*>(dK + off);
            const float4 km = *reinterpret_cast<const float4*>(KM + ((size_t)(b * L_ + k) * 64 + c));
            float s = qv0 * (km.x + t1.x + t2.x) + qv1 * (km.y + t1.y + t2.y)
                    + qv2 * (km.z + t1.z + t2.z) + qv3 * (km.w + t1.w + t2.w);
            // reduce across the 8 lanes (same k, same head): c4 bits 0..2
            s += __shfl_xor(s, 1);
            s += __shfl_xor(s, 2);
            s += __shfl_xor(s, 4);
            if ((c4 & 7) == 0) sScore[h][k] = s * 0.17677669529663687f; // 1/sqrt(32)
        }
    }
    __syncthreads();

    // ---- masked softmax over k (wave 0 -> head 0, wave 1 -> head 1) ----
    const float NEGV = -4294967295.0f;    // -2^32 + 1 (rounds to -2^32 in f32, same as ref)
    const int wv = tid >> 6, lane = tid & 63;
    if (wv < NH_) {
        const bool rowmask = time_mask[b * L_ + q] != 0;
        float vals[4];
        float m = -3.4e38f;
#pragma unroll
        for (int i = 0; i < 4; i++) {
            const int k = lane + i * 64;
            if (k < L_) {
                float s = sScore[wv][k];
                if (rowmask || attn_mask[q * L_ + k] != 0) s = NEGV;
                vals[i] = s;
                m = fmaxf(m, s);
            } else vals[i] = -3.4e38f;
        }
#pragma unroll
        for (int off = 32; off >= 1; off >>= 1) m = fmaxf(m, __shfl_xor(m, off));
        float sum = 0.f;
#pragma unroll
        for (int i = 0; i < 4; i++) {
            const int k = lane + i * 64;
            if (k < L_) {
                const float e = __expf(vals[i] - m);
                sum += e;
                sScore[wv][k] = e;
            }
        }
#pragma unroll
        for (int off = 32; off >= 1; off >>= 1) sum += __shfl_xor(sum, off);
        const float inv = 1.0f / sum;
#pragma unroll
        for (int i = 0; i < 4; i++) {
            const int k = lane + i * 64;
            if (k < L_) sScore[wv][k] *= inv;
        }
    }
    __syncthreads();

    // ---- PV ----
    float a0 = 0.f, a1 = 0.f, a2 = 0.f, a3 = 0.f;
    for (int k0 = 0; k0 < L_; k0 += 16) {
        const int k = k0 + krow;
        if (k < L_) {
            const size_t off = bigbase + (size_t)k * 64 + c;
            const float4 v1 = *reinterpret_cast<const float4*>(tV + off);
            const float4 v2 = *reinterpret_cast<const float4*>(dV + off);
            const float4 vm = *reinterpret_cast<const float4*>(VM + ((size_t)(b * L_ + k) * 64 + c));
            const float a = sScore[h][k];
            a0 += a * (vm.x + v1.x + v2.x);
            a1 += a * (vm.y + v1.y + v2.y);
            a2 += a * (vm.z + v1.z + v2.z);
            a3 += a * (vm.w + v1.w + v2.w);
        }
    }
    sRed[krow][c]     = a0;
    sRed[krow][c + 1] = a1;
    sRed[krow][c + 2] = a2;
    sRed[krow][c + 3] = a3;
    __syncthreads();
    if (tid < 64) {
        float s = 0.f;
#pragma unroll
        for (int r = 0; r < 16; r++) s += sRed[r][tid];
        out[(size_t)bq * 64 + tid] = s;
    }
}

// ---------------------------------------------------------------------------
extern "C" void kernel_launch(void* const* d_in, const int* in_sizes, int n_in,
                              void* d_out, int out_size, void* d_ws, size_t ws_size,
                              hipStream_t stream) {
    const float* queries = (const float*)d_in[0];
    const float* keys    = (const float*)d_in[1];
    const int* time_mask = (const int*)d_in[2];
    const int* attn_mask = (const int*)d_in[3];
    const float* tK   = (const float*)d_in[4];
    const float* tV   = (const float*)d_in[5];
    const float* dK   = (const float*)d_in[6];
    const float* dV   = (const float*)d_in[7];
    const float* absK = (const float*)d_in[8];
    const float* absV = (const float*)d_in[9];
    const float* Wq = (const float*)d_in[10];
    const float* bq = (const float*)d_in[11];
    const float* Wk = (const float*)d_in[12];
    const float* bk = (const float*)d_in[13];
    const float* Wv = (const float*)d_in[14];
    const float* bv = (const float*)d_in[15];
    float* out = (float*)d_out;

    // workspace: QM, KM, VM each [B,L,H] f32 (2.46 MB total)
    float* QM = (float*)d_ws;
    float* KM = QM + (size_t)B_ * L_ * H_;
    float* VM = KM + (size_t)B_ * L_ * H_;

    proj_kernel<<<(B_ * L_) / 4, 256, 0, stream>>>(queries, keys, absK, absV,
                                                   Wq, bq, Wk, bk, Wv, bv,
                                                   QM, KM, VM);
    attn_kernel<<<B_ * L_, 256, 0, stream>>>(QM, KM, VM, tK, dK, tV, dV,
                                             time_mask, attn_mask, out);
}